// Round 13
// baseline (691.087 us; speedup 1.0000x reference)
//
#include <hip/hip_runtime.h>

#define N_NODES 20000
#define E_EDGES 640000
#define R_REL   64
#define B_BASES 16

__device__ inline float bf2f(unsigned short v) {
    unsigned int u = ((unsigned int)v) << 16;
    return __uint_as_float(u);
}
__device__ inline unsigned short f2bf(float f) {
    unsigned int u = __float_as_uint(f);
    unsigned int r = (u + 0x7FFF + ((u >> 16) & 1)) >> 16;  // RNE
    return (unsigned short)r;
}

// ---- W_rel (f32 [r][i][o]) + W_relT (bf16 [r][o][i]) from basis combination ----
// bf16 LDS transpose buffer: 33.8 KB (< 64 KiB limit).
__global__ void k_wrel(const float* weight, const float* w_comp,
                       float* W_rel, unsigned short* wrelT)
{
    __shared__ unsigned short ldsT[128 * 132];   // [i][o] padded, scalar access
    int r = blockIdx.x, t = threadIdx.x;
    float wc[B_BASES];
    for (int b = 0; b < B_BASES; b++) wc[b] = w_comp[r * B_BASES + b];
    for (int c = 0; c < 8; c++) {
        int f = (c * 256 + t) * 8;
        float acc[8] = {0,0,0,0,0,0,0,0};
        for (int b = 0; b < B_BASES; b++) {
            const float* wp = weight + b * 16384 + f;
            float4 w0 = *(const float4*)wp;
            float4 w1 = *(const float4*)(wp + 4);
            acc[0] += wc[b] * w0.x; acc[1] += wc[b] * w0.y;
            acc[2] += wc[b] * w0.z; acc[3] += wc[b] * w0.w;
            acc[4] += wc[b] * w1.x; acc[5] += wc[b] * w1.y;
            acc[6] += wc[b] * w1.z; acc[7] += wc[b] * w1.w;
        }
        int i = f >> 7, o = f & 127;
        for (int j = 0; j < 8; j++) {
            ldsT[i * 132 + o + j] = f2bf(acc[j]);
            W_rel[(size_t)r * 16384 + f + j] = acc[j];
        }
    }
    __syncthreads();
    int o = t >> 1, i0 = (t & 1) * 64;
    for (int g = 0; g < 8; g++) {
        uint4 v;
        unsigned int pk[4];
        for (int u = 0; u < 4; u++) {
            unsigned int lo = ldsT[(i0 + g * 8 + u * 2) * 132 + o];
            unsigned int hi = ldsT[(i0 + g * 8 + u * 2 + 1) * 132 + o];
            pk[u] = lo | (hi << 16);
        }
        v.x = pk[0]; v.y = pk[1]; v.z = pk[2]; v.w = pk[3];
        *(uint4*)&wrelT[(size_t)r * 16384 + o * 128 + i0 + g * 8] = v;
    }
}

// ---- x -> bf16 copy ----
__global__ void k_xbf16(const float* x, unsigned short* xbf)
{
    int idx = blockIdx.x * 256 + threadIdx.x;   // exactly N*128 = 2,560,000
    xbf[idx] = f2bf(x[idx]);
}

// ---- zero counters ----
__global__ void k_zero(int* counts, int* counts2)
{
    int idx = blockIdx.x * 256 + threadIdx.x;
    if (idx < R_REL) counts[idx] = 0;
    if (idx < N_NODES) counts2[idx] = 0;
}

// ---- etype histogram (R9-proven) ----
__global__ void k_hist(const int* etypes, int* counts)
{
    __shared__ int h[R_REL];
    int t = threadIdx.x;
    if (t < R_REL) h[t] = 0;
    __syncthreads();
    int e = blockIdx.x * 256 + t;
    atomicAdd(&h[etypes[e]], 1);
    __syncthreads();
    if (t < R_REL && h[t] != 0) atomicAdd(&counts[t], h[t]);
}

// ---- dst histogram (R9-proven) ----
__global__ void k_hist2(const int* dst, int* counts2)
{
    int e = blockIdx.x * 256 + threadIdx.x;
    atomicAdd(&counts2[dst[e]], 1);
}

// ---- serial 64-entry scan (R9-proven) ----
__global__ void k_scan(const int* counts, int* offsets, int* cursor, int* co)
{
    if (threadIdx.x == 0) {
        int run = 0, c = 0;
        for (int r = 0; r < R_REL; r++) {
            offsets[r] = run; cursor[r] = run; co[r] = c;
            run += counts[r];
            c   += (counts[r] + 63) >> 6;
        }
        offsets[R_REL] = run; co[R_REL] = c;
    }
}

// ---- single-block parallel scan over 20000 dst counts (R9-proven) ----
__global__ void k_scan2(const int* counts2, int* off2, int* cursor2)
{
    __shared__ int part[256];
    int t = threadIdx.x;
    int lo = t * 79;
    int hi = lo + 79; if (hi > N_NODES) hi = N_NODES;
    int s = 0;
    for (int i = lo; i < hi; i++) s += counts2[i];
    part[t] = s;
    __syncthreads();
    for (int d = 1; d < 256; d <<= 1) {
        int v = (t >= d) ? part[t - d] : 0;
        __syncthreads();
        part[t] += v;
        __syncthreads();
    }
    int run = part[t] - s;
    for (int i = lo; i < hi; i++) {
        off2[i] = run; cursor2[i] = run;
        run += counts2[i];
    }
    if (t == 255) off2[N_NODES] = run;
}

// ---- bucket scatter (R9-proven) ----
__global__ void k_scatter(const int* etypes, int* cursor, int* perm)
{
    __shared__ int h[R_REL];
    __shared__ int base[R_REL];
    int t = threadIdx.x;
    if (t < R_REL) h[t] = 0;
    __syncthreads();
    int e = blockIdx.x * 256 + t;
    int et = etypes[e];
    int rank = atomicAdd(&h[et], 1);
    __syncthreads();
    if (t < R_REL && h[t] != 0) base[t] = atomicAdd(&cursor[t], h[t]);
    __syncthreads();
    perm[base[et] + rank] = e;
}

// ---- pos2[etype-order position p] = dst-sorted slot (R9-proven) ----
__global__ void k_rank2(const int* perm, const int* dst, int* cursor2, int* pos2)
{
    int p = blockIdx.x * 256 + threadIdx.x;
    int eid = perm[p];
    int slot = atomicAdd(&cursor2[dst[eid]], 1);
    pos2[p] = slot;
}

// ---- Phase A: f32 VALU GEMM (R9-proven byte-for-byte) ----
__global__ void k_edge_msg(const float* x, const float* W_rel, const float* norm,
                           const int* src, const int* perm, const int* pos2,
                           const int* offsets, const int* co, unsigned short* msg)
{
    __shared__ float4 WfS[2048];
    __shared__ float4 xsS[1024];
    __shared__ int coS[R_REL + 1];
    __shared__ int srcS[64];
    __shared__ float normS[64];
    int t = threadIdx.x, bid = blockIdx.x;
    if (t <= R_REL) coS[t] = co[t];
    __syncthreads();
    if (bid >= coS[R_REL]) return;
    int r = 0;
    while (bid >= coS[r + 1]) r++;
    int e0 = offsets[r] + (bid - coS[r]) * 64;
    int cnt = offsets[r + 1] - e0;
    if (cnt > 64) cnt = 64;
    if (t < 64) {
        if (t < cnt) {
            int eid = perm[e0 + t];
            srcS[t] = src[eid]; normS[t] = norm[eid];
        } else { srcS[t] = 0; normS[t] = 0.0f; }
    }
    const float* xsf = (const float*)xsS;
    int q  = t & 31;
    int eb = t >> 5;
    float4 acc[8];
    for (int k = 0; k < 8; k++) { acc[k].x = 0.f; acc[k].y = 0.f; acc[k].z = 0.f; acc[k].w = 0.f; }
    for (int h = 0; h < 2; h++) {
        __syncthreads();
        const float4* Wsrc = (const float4*)(W_rel + (size_t)r * 16384 + h * 8192);
        for (int p = 0; p < 8; p++) WfS[p * 256 + t] = Wsrc[p * 256 + t];
        for (int p = 0; p < 4; p++) {
            int idx = p * 256 + t;
            int e = idx >> 4, c = idx & 15;
            xsS[idx] = ((const float4*)(x + srcS[e] * 128 + h * 64))[c];
        }
        __syncthreads();
        for (int i = 0; i < 64; i++) {
            float4 wv = WfS[i * 32 + q];
            for (int k = 0; k < 8; k++) {
                float xv = xsf[(eb + 8 * k) * 64 + i];
                acc[k].x += xv * wv.x;
                acc[k].y += xv * wv.y;
                acc[k].z += xv * wv.z;
                acc[k].w += xv * wv.w;
            }
        }
    }
    for (int k = 0; k < 8; k++) {
        int e = eb + 8 * k;
        if (e < cnt) {
            float nrm = normS[e];
            int slot = pos2[e0 + e];
            unsigned int p0 = (unsigned int)f2bf(acc[k].x * nrm)
                            | ((unsigned int)f2bf(acc[k].y * nrm) << 16);
            unsigned int p1 = (unsigned int)f2bf(acc[k].z * nrm)
                            | ((unsigned int)f2bf(acc[k].w * nrm) << 16);
            unsigned int* row = (unsigned int*)(msg + (size_t)slot * 128) + q * 2;
            row[0] = p0; row[1] = p1;
        }
    }
}

// ---- self-loop GEMM (R9-proven) ----
__global__ void k_selfgemm(const float* x, const float* loop_w, const float* bias,
                           float* out)
{
    __shared__ float4 WfS[2048];
    __shared__ float4 xsS[1024];
    int t = threadIdx.x, bid = blockIdx.x;
    int n0 = bid * 64;
    const float* xsf = (const float*)xsS;
    int q  = t & 31;
    int eb = t >> 5;
    float4 acc[8];
    for (int k = 0; k < 8; k++) { acc[k].x = 0.f; acc[k].y = 0.f; acc[k].z = 0.f; acc[k].w = 0.f; }
    for (int h = 0; h < 2; h++) {
        __syncthreads();
        const float4* Wsrc = (const float4*)(loop_w + h * 8192);
        for (int p = 0; p < 8; p++) WfS[p * 256 + t] = Wsrc[p * 256 + t];
        for (int p = 0; p < 4; p++) {
            int idx = p * 256 + t;
            int e = idx >> 4, c = idx & 15;
            int n = n0 + e; if (n >= N_NODES) n = N_NODES - 1;
            xsS[idx] = ((const float4*)(x + n * 128 + h * 64))[c];
        }
        __syncthreads();
        for (int i = 0; i < 64; i++) {
            float4 wv = WfS[i * 32 + q];
            for (int k = 0; k < 8; k++) {
                float xv = xsf[(eb + 8 * k) * 64 + i];
                acc[k].x += xv * wv.x;
                acc[k].y += xv * wv.y;
                acc[k].z += xv * wv.z;
                acc[k].w += xv * wv.w;
            }
        }
    }
    float4 b4 = *((const float4*)(bias + q * 4));
    for (int k = 0; k < 8; k++) {
        int n = n0 + eb + 8 * k;
        if (n < N_NODES) {
            float4 v;
            v.x = acc[k].x + b4.x;
            v.y = acc[k].y + b4.y;
            v.z = acc[k].z + b4.z;
            v.w = acc[k].w + b4.w;
            *((float4*)(out + (size_t)n * 128 + q * 4)) = v;
        }
    }
}

// ---- msg reduction (R9-proven) ----
__global__ void k_msgsum(const unsigned short* msg, const int* off2, float* out)
{
    int n = blockIdx.x;
    int o = threadIdx.x;
    int m0 = off2[n], m1 = off2[n + 1];
    float acc = 0.0f;
    for (int j = m0; j < m1; j++)
        acc += bf2f(msg[(size_t)j * 128 + o]);
    float val = out[(size_t)n * 128 + o] + acc;
    if (val < 0.0f) val = 0.0f;
    out[(size_t)n * 128 + o] = val;
}

extern "C" void kernel_launch(void* const* d_in, const int* in_sizes, int n_in,
                              void* d_out, int out_size, void* d_ws, size_t ws_size,
                              hipStream_t stream)
{
    const float* x      = (const float*)d_in[0];
    const float* weight = (const float*)d_in[1];
    const float* w_comp = (const float*)d_in[2];
    const float* h_bias = (const float*)d_in[3];
    const float* loop_w = (const float*)d_in[4];
    const float* norm   = (const float*)d_in[5];
    const int* src    = (const int*)d_in[6];
    const int* dst    = (const int*)d_in[7];
    const int* etypes = (const int*)d_in[8];
    float* out = (float*)d_out;

    char* ws = (char*)d_ws;
    size_t off = 0;
    float* W_rel = (float*)(ws + off);            off += (size_t)R_REL * 16384 * 4;
    unsigned short* wrelT = (unsigned short*)(ws + off); off += (size_t)R_REL * 16384 * 2;
    unsigned short* xbf   = (unsigned short*)(ws + off); off += (size_t)N_NODES * 128 * 2;
    int* perm    = (int*)(ws + off);   off += (size_t)E_EDGES * 4;
    int* pos2    = (int*)(ws + off);   off += (size_t)E_EDGES * 4;
    int* counts  = (int*)(ws + off);   off += 64 * 4;
    int* offsets = (int*)(ws + off);   off += 68 * 4;
    int* cursor  = (int*)(ws + off);   off += 64 * 4;
    int* co      = (int*)(ws + off);   off += 68 * 4;
    int* counts2 = (int*)(ws + off);   off += (size_t)N_NODES * 4;
    int* off2    = (int*)(ws + off);   off += (size_t)(N_NODES + 1) * 4;
    int* cursor2 = (int*)(ws + off);   off += (size_t)N_NODES * 4;
    unsigned short* msg = (unsigned short*)(ws + off);

    k_wrel<<<R_REL, 256, 0, stream>>>(weight, w_comp, W_rel, wrelT);
    k_xbf16<<<(N_NODES * 128) / 256, 256, 0, stream>>>(x, xbf);
    k_zero<<<(N_NODES + 255) / 256, 256, 0, stream>>>(counts, counts2);
    k_hist<<<E_EDGES / 256, 256, 0, stream>>>(etypes, counts);
    k_hist2<<<E_EDGES / 256, 256, 0, stream>>>(dst, counts2);
    k_scan<<<1, 64, 0, stream>>>(counts, offsets, cursor, co);
    k_scan2<<<1, 256, 0, stream>>>(counts2, off2, cursor2);
    k_scatter<<<E_EDGES / 256, 256, 0, stream>>>(etypes, cursor, perm);
    k_rank2<<<E_EDGES / 256, 256, 0, stream>>>(perm, dst, cursor2, pos2);
    k_edge_msg<<<E_EDGES / 64 + R_REL, 256, 0, stream>>>(
        x, W_rel, norm, src, perm, pos2, offsets, co, msg);
    k_selfgemm<<<(N_NODES + 63) / 64, 256, 0, stream>>>(x, loop_w, h_bias, out);
    k_msgsum<<<N_NODES, 128, 0, stream>>>(msg, off2, out);
}